// Round 7
// baseline (476.779 us; speedup 1.0000x reference)
//
#include <hip/hip_runtime.h>

#define NB_B 2
#define NB_S 2048
#define NB_D 1024
#define NB_H 16
#define NB_HD 64
#define NB_ROT 32

typedef __bf16 bf16x8 __attribute__((ext_vector_type(8)));
typedef float f32x4 __attribute__((ext_vector_type(4)));

__device__ inline f32x4 mfma16(bf16x8 a, bf16x8 b, f32x4 c) {
  return __builtin_amdgcn_mfma_f32_16x16x32_bf16(a, b, c, 0, 0, 0);
}

// float -> bf16 bits, round-to-nearest-even (finite inputs)
__device__ inline unsigned short f2bf(float f) {
  unsigned u = __builtin_bit_cast(unsigned, f);
  unsigned r = (u + 0x7fffu + ((u >> 16) & 1u)) >> 16;
  return (unsigned short)r;
}
__device__ inline float bf2f(unsigned short h) {
  return __builtin_bit_cast(float, (unsigned)h << 16);
}

// async global->LDS, 16 B per lane; lds dest = uniform base + lane*16
__device__ inline void async16(const void* g, void* l) {
  __builtin_amdgcn_global_load_lds((const __attribute__((address_space(1))) unsigned int*)g,
                                   (__attribute__((address_space(3))) unsigned int*)l, 16, 0, 0);
}

// ---------------- merged prep: hs-split + weight-split + rope table ----------------
__global__ __launch_bounds__(256) void k_prep(
    const float* __restrict__ hs, const float* __restrict__ w0,
    const float* __restrict__ w1, const float* __restrict__ w2,
    const float* __restrict__ w3, ushort* __restrict__ Ahi,
    ushort* __restrict__ Alo, ushort* __restrict__ Whi,
    ushort* __restrict__ Wlo, float* __restrict__ tab) {
  const int bid = blockIdx.x;
  const int tid = threadIdx.x;
  if (bid < 4096) {
    const float* src;
    ushort *dh, *dl;
    int i;
    if (bid < 2048) {
      i = (bid * 256 + tid) * 8;
      src = hs; dh = Ahi; dl = Alo;
    } else {
      const int gi = ((bid - 2048) * 256 + tid) * 8;  // over 4M weight floats
      const int wsel = gi >> 20;
      i = gi & ((1 << 20) - 1);
      src = (wsel == 0) ? w0 : (wsel == 1) ? w1 : (wsel == 2) ? w2 : w3;
      dh = Whi + ((size_t)wsel << 20);
      dl = Wlo + ((size_t)wsel << 20);
    }
    float4 a = *(const float4*)(src + i);
    float4 b = *(const float4*)(src + i + 4);
    float v[8] = {a.x, a.y, a.z, a.w, b.x, b.y, b.z, b.w};
    ushort h[8], l[8];
#pragma unroll
    for (int k = 0; k < 8; ++k) {
      h[k] = f2bf(v[k]);
      l[k] = f2bf(v[k] - bf2f(h[k]));
    }
    ushort4 h0 = {h[0], h[1], h[2], h[3]}, h1 = {h[4], h[5], h[6], h[7]};
    ushort4 l0 = {l[0], l[1], l[2], l[3]}, l1 = {l[4], l[5], l[6], l[7]};
    *(ushort4*)(dh + i) = h0; *(ushort4*)(dh + i + 4) = h1;
    *(ushort4*)(dl + i) = l0; *(ushort4*)(dl + i + 4) = l1;
  } else {
    const int i = (bid - 4096) * 256 + tid;  // < 32768 rope pairs
    const int s = i >> 4;
    const int pp = i & 15;
    float inv = powf(10000.0f, -(2.0f * (float)pp) / (float)NB_ROT);
    float a = (float)s * inv;
    tab[2 * i + 0] = sinf(a);
    tab[2 * i + 1] = cosf(a);
  }
}

// ---------------- one K-step of MFMA work on pre-read fragments ----------------
// TRC=0: acc[m][n] = A*W^T ;  TRC=1: acc[n][m] = W*A^T (operand swap)
template <int TRC>
__device__ __forceinline__ void gemm_mfma_regs(const bf16x8 (&fah)[4], const bf16x8 (&fal)[4],
                                               const bf16x8 (&fwh)[4], const bf16x8 (&fwl)[4],
                                               f32x4 (&acc)[4][4]) {
  __builtin_amdgcn_s_setprio(1);
#pragma unroll
  for (int i = 0; i < 4; ++i)
#pragma unroll
    for (int j = 0; j < 4; ++j) {
      if (TRC == 0) {
        f32x4 c = acc[i][j];
        c = mfma16(fah[i], fwh[j], c);
        c = mfma16(fah[i], fwl[j], c);
        c = mfma16(fal[i], fwh[j], c);
        acc[i][j] = c;
      } else {
        f32x4 c = acc[j][i];
        c = mfma16(fwh[j], fah[i], c);
        c = mfma16(fwh[j], fal[i], c);
        c = mfma16(fwl[j], fah[i], c);
        acc[j][i] = c;
      }
    }
  __builtin_amdgcn_s_setprio(0);
}

// ---------------- split-bf16 MFMA GEMM  C = A @ W^T ----------------
// 128x128 tile, BK=32, 4 waves x (64x64), single 32 KB LDS buffer,
// early-stage (issue next tile's loads before MFMA), (4,2) XCD partition.
// JOB=0: merged QKV, grid 768.  z: 0=Q (rope+1/8, bf16 (bh,s,hd), TR)
//        1=K (rope, TR)  2=V (bf16 Vt (bh,hd,S))
// JOB=1: wo split-K, grid 512. kh selects K-half; fp32 out to O0 (kh=0) / O1 (kh=1)
template <int JOB>
__global__ __launch_bounds__(256, 3) void k_gemm_mfma(
    const ushort* __restrict__ Ahi, const ushort* __restrict__ Alo,
    const ushort* __restrict__ Whi, const ushort* __restrict__ Wlo,
    void* __restrict__ O0, void* __restrict__ O1, void* __restrict__ O2,
    const float* __restrict__ tab) {
  __shared__ __align__(16) ushort SB[4][4096];  // 32 KB: {Ah, Al, Wh, Wl}

  const int tid = threadIdx.x;
  const int wid = tid >> 6;
  const int lane = tid & 63;
  const int lq = lane & 15;
  const int g = lane >> 4;

  // (4,2) XCD partition: mg = m-quarter, ng = col-half
  const int HC = (JOB == 0) ? 12 : 8;  // cols per XCD col-half
  const int p = blockIdx.x;
  const int xcd = p & 7;
  const int mg = xcd >> 1, ng = xcd & 1;
  const int j = p >> 3;
  const int m0 = ((mg << 3) + j / HC) << 7;
  const int c = ng * HC + j % HC;       // JOB0: 0..23 (z,n); JOB1: 0..15 (kh,n)
  const int n0 = (c & 7) << 7;
  const int zz = (JOB == 0) ? (c >> 3) : 0;   // weight offset selector
  const int kh = (JOB == 0) ? 0 : (c >> 3);
  const int kbeg = kh << 9;
  const int kend = kbeg + ((JOB == 0) ? 1024 : 512);
  const bool tr = (JOB == 0) && (c < 16);     // Q,K use swapped operands

  const ushort* wh = Whi + ((size_t)zz << 20);
  const ushort* wl = Wlo + ((size_t)zz << 20);

  // wave wid stages one region {0:Ah, 1:Al, 2:Wh, 3:Wl}
  const ushort* gsb;
  int rowb;
  if (wid == 0)      { gsb = Ahi; rowb = m0; }
  else if (wid == 1) { gsb = Alo; rowb = m0; }
  else if (wid == 2) { gsb = wh;  rowb = n0; }
  else               { gsb = wl;  rowb = n0; }
  const ushort* gp = gsb + (size_t)(rowb + lq) * NB_D + g * 8;

  f32x4 acc[4][4];
#pragma unroll
  for (int i = 0; i < 4; ++i)
#pragma unroll
    for (int jj = 0; jj < 4; ++jj) acc[i][jj] = (f32x4){0.f, 0.f, 0.f, 0.f};

  const int ma = (wid & 1) * 4;
  const int nb = (wid >> 1) * 4;

  // prologue: stage first K-tile
#pragma unroll
  for (int jj = 0; jj < 8; ++jj)
    async16(gp + kbeg + (size_t)jj * 16 * NB_D, &SB[wid][jj * 512]);
  __syncthreads();  // vmcnt(0) drain: tile 0 landed

  for (int k0 = kbeg; k0 < kend; k0 += 32) {
    // read all fragments for this K-step into registers
    bf16x8 fah[4], fal[4], fwh[4], fwl[4];
#pragma unroll
    for (int i = 0; i < 4; ++i) {
      fah[i] = *(const bf16x8*)(&SB[0][(ma + i) * 512 + lane * 8]);
      fal[i] = *(const bf16x8*)(&SB[1][(ma + i) * 512 + lane * 8]);
      fwh[i] = *(const bf16x8*)(&SB[2][(nb + i) * 512 + lane * 8]);
      fwl[i] = *(const bf16x8*)(&SB[3][(nb + i) * 512 + lane * 8]);
    }
    __syncthreads();  // all waves done reading -> buffer free for overwrite
    if (k0 + 32 < kend) {  // issue next tile's loads, then compute (latency cover)
#pragma unroll
      for (int jj = 0; jj < 8; ++jj)
        async16(gp + (k0 + 32) + (size_t)jj * 16 * NB_D, &SB[wid][jj * 512]);
    }
    if (tr) gemm_mfma_regs<1>(fah, fal, fwh, fwl, acc);
    else    gemm_mfma_regs<0>(fah, fal, fwh, fwl, acc);
    __syncthreads();  // vmcnt(0) drain: next tile landed
  }

  const int wm = (wid & 1) * 64;
  const int wn = (wid >> 1) * 64;

  if (JOB == 1) {  // wo partial: fp32 row-major to out (kh=0) or scratch (kh=1)
    float* outp = (kh == 0) ? (float*)O0 : (float*)O1;
#pragma unroll
    for (int i = 0; i < 4; ++i)
#pragma unroll
      for (int jj = 0; jj < 4; ++jj) {
        const int col = n0 + wn + jj * 16 + lq;
#pragma unroll
        for (int r = 0; r < 4; ++r) {
          const int row = m0 + wm + i * 16 + 4 * g + r;
          outp[(size_t)row * NB_D + col] = acc[i][jj][r];
        }
      }
  } else if (zz == 2) {  // V -> bf16 transposed (bh, hd, S)
    ushort* ov = (ushort*)O2;
#pragma unroll
    for (int i = 0; i < 4; ++i) {
      const int gm0 = m0 + wm + i * 16 + 4 * g;
      const int b = gm0 >> 11;
      const int s0 = gm0 & (NB_S - 1);
#pragma unroll
      for (int jj = 0; jj < 4; ++jj) {
        const int gn = n0 + wn + jj * 16 + lq;
        const int hh = gn >> 6;
        const int d0 = gn & 63;
        ushort4 pk = {f2bf(acc[i][jj][0]), f2bf(acc[i][jj][1]),
                      f2bf(acc[i][jj][2]), f2bf(acc[i][jj][3])};
        *(ushort4*)(ov + ((size_t)((b * NB_H + hh) * NB_HD + d0)) * NB_S + s0) = pk;
      }
    }
  } else {  // Q/K: rope lane-local, bf16 (bh, s, hd); Q scaled 1/8
    void* O = (zz == 0) ? O0 : O1;
#pragma unroll
    for (int jn = 0; jn < 4; ++jn) {
      const int gn0 = n0 + wn + jn * 16 + 4 * g;
      const int hh = gn0 >> 6;
      const int d0 = gn0 & 63;
#pragma unroll
      for (int im = 0; im < 4; ++im) {
        const int gm = m0 + wm + im * 16 + lq;
        const int b = gm >> 11;
        const int s = gm & (NB_S - 1);
        float v0 = acc[jn][im][0], v1 = acc[jn][im][1];
        float v2 = acc[jn][im][2], v3 = acc[jn][im][3];
        if (d0 < NB_ROT) {
          const int p0 = d0 >> 1;
          const float2 t0 = *(const float2*)(tab + ((s * 16 + p0) << 1));
          const float2 t1 = *(const float2*)(tab + ((s * 16 + p0 + 1) << 1));
          const float n0v = v0 * t0.y - v1 * t0.x;
          const float n1v = v1 * t0.y + v0 * t0.x;
          const float n2v = v2 * t1.y - v3 * t1.x;
          const float n3v = v3 * t1.y + v2 * t1.x;
          v0 = n0v; v1 = n1v; v2 = n2v; v3 = n3v;
        }
        if (zz == 0) { v0 *= 0.125f; v1 *= 0.125f; v2 *= 0.125f; v3 *= 0.125f; }
        ushort4 pk = {f2bf(v0), f2bf(v1), f2bf(v2), f2bf(v3)};
        *(ushort4*)((ushort*)O + ((size_t)(b * NB_H + hh) * NB_S + s) * NB_HD + d0) = pk;
      }
    }
  }
}

// ---------------- split-K reducer: out += p1 ----------------
__global__ __launch_bounds__(256) void k_red(float* __restrict__ out,
                                             const float* __restrict__ p1) {
  const int i = (blockIdx.x * 256 + threadIdx.x) * 8;
  float4 a0 = *(float4*)(out + i);
  float4 a1 = *(float4*)(out + i + 4);
  const float4 b0 = *(const float4*)(p1 + i);
  const float4 b1 = *(const float4*)(p1 + i + 4);
  a0.x += b0.x; a0.y += b0.y; a0.z += b0.z; a0.w += b0.w;
  a1.x += b1.x; a1.y += b1.y; a1.z += b1.z; a1.w += b1.w;
  *(float4*)(out + i) = a0;
  *(float4*)(out + i + 4) = a1;
}

// ---------------- bf16 MFMA causal flash attention ----------------
// 4 waves x 16 q-rows; KVBLK=64; double-buffered async K/V staging
// (pre-swizzled global src, linear LDS dest); diagonal-only masking;
// defer-max (THR=8); XCD-balanced (qt,bh) mapping. Q pre-scaled by 1/8.
__global__ __launch_bounds__(256) void k_attn(
    const ushort* __restrict__ Q, const ushort* __restrict__ K,
    const ushort* __restrict__ Vt, ushort* __restrict__ OH,
    ushort* __restrict__ OL) {
  __shared__ __align__(16) unsigned char KsB[2][8192];  // [kk][hd] bf16, swz
  __shared__ __align__(16) unsigned char VsB[2][8192];  // [hd][kk] bf16, swz
  __shared__ __align__(16) unsigned char PsB[8192];     // 4w x [16 q][64 k] bf16, swz

  const int tid = threadIdx.x;
  const int wid = tid >> 6;
  const int lane = tid & 63;
  const int lq = lane & 15;
  const int g = lane >> 4;

  // XCD-balanced mapping: 4 same-bh blocks per CU, qt-set sums to 66
  const int p = blockIdx.x + 32 * blockIdx.y;
  const int xcd = p & 7;
  const int q = p >> 3;
  const int bh = 4 * xcd + (q & 3);
  const int qi = q >> 2;
  const int hi = qi >> 3, lo = qi & 7;
  const int qt = (hi == 0) ? lo : (hi == 1) ? 31 - lo : (hi == 2) ? 8 + lo : 23 - lo;

  const int q0 = qt * 64;
  const int qg = q0 + wid * 16 + lq;

  const ushort* Kb = K + (size_t)bh * NB_S * NB_HD;
  const ushort* Vb = Vt + (size_t)bh * NB_HD * NB_S;

  const ushort* Qrow = Q + ((size_t)bh * NB_S + qg) * NB_HD;
  const bf16x8 qf0 = *(const bf16x8*)(Qrow + 8 * g);
  const bf16x8 qf1 = *(const bf16x8*)(Qrow + 32 + 8 * g);

  const int srow = lane >> 3;
  const int schk = (lane & 7) ^ srow;

  float m = -INFINITY;
  float l = 0.0f;
  f32x4 o[4];
#pragma unroll
  for (int ht = 0; ht < 4; ++ht) o[ht] = (f32x4){0.f, 0.f, 0.f, 0.f};

  const int swz = (lq & 7) << 4;
  unsigned char* Pw = PsB + wid * 2048;

#pragma unroll
  for (int jj = 0; jj < 2; ++jj) {
    const int rb = 16 * wid + 8 * jj;
    const int row = rb + srow;
    async16(Kb + (size_t)row * NB_HD + schk * 8, KsB[0] + rb * 128);
    async16(Vb + (size_t)row * NB_S + schk * 8, VsB[0] + rb * 128);
  }
  __syncthreads();

  for (int t = 0; t <= qt; ++t) {
    const int cur = t & 1;
    if (t < qt) {
      const int k1 = (t + 1) * 64;
#pragma unroll
      for (int jj = 0; jj < 2; ++jj) {
        const int rb = 16 * wid + 8 * jj;
        const int row = rb + srow;
        async16(Kb + (size_t)(k1 + row) * NB_HD + schk * 8, KsB[cur ^ 1] + rb * 128);
        async16(Vb + (size_t)row * NB_S + k1 + schk * 8, VsB[cur ^ 1] + rb * 128);
      }
    }
    const unsigned char* Ks = KsB[cur];
    const unsigned char* Vs = VsB[cur];

    f32x4 sc[4];
    __builtin_amdgcn_s_setprio(1);
#pragma unroll
    for (int c = 0; c < 4; ++c) {
      const int rb = (16 * c + lq) << 7;
      const bf16x8 a0 = *(const bf16x8*)(Ks + ((rb + (g << 4)) ^ swz));
      const bf16x8 a1 = *(const bf16x8*)(Ks + ((rb + 64 + (g << 4)) ^ swz));
      f32x4 zz = {0.f, 0.f, 0.f, 0.f};
      zz = mfma16(a0, qf0, zz);
      zz = mfma16(a1, qf1, zz);
      sc[c] = zz;
    }
    __builtin_amdgcn_s_setprio(0);

    float vals[4][4];
    if (t == qt) {
      const int k0 = t * 64;
#pragma unroll
      for (int c = 0; c < 4; ++c)
#pragma unroll
        for (int r = 0; r < 4; ++r) {
          const int kk = k0 + 16 * c + 4 * g + r;
          vals[c][r] = (kk <= qg) ? sc[c][r] : -INFINITY;
        }
    } else {
#pragma unroll
      for (int c = 0; c < 4; ++c)
#pragma unroll
        for (int r = 0; r < 4; ++r) vals[c][r] = sc[c][r];
    }

    float pm = vals[0][0];
#pragma unroll
    for (int c = 0; c < 4; ++c)
#pragma unroll
      for (int r = 0; r < 4; ++r) pm = fmaxf(pm, vals[c][r]);
    pm = fmaxf(pm, __shfl_xor(pm, 16));
    pm = fmaxf(pm, __shfl_xor(pm, 32));

    float psum = 0.0f;
    if (__any(pm - m > 8.0f)) {
      const float mnew = fmaxf(m, pm);
      const float alpha = __expf(m - mnew);
#pragma unroll
      for (int c = 0; c < 4; ++c)
#pragma unroll
        for (int r = 0; r < 4; ++r) {
          const float pv = __expf(vals[c][r] - mnew);
          vals[c][r] = pv;
          psum += pv;
        }
      psum += __shfl_xor(psum, 16);
      psum += __shfl_xor(psum, 32);
      l = l * alpha + psum;
      m = mnew;
#pragma unroll
      for (int r = 0; r < 4; ++r) {
        const float ar = __shfl(alpha, 4 * g + r);
#pragma unroll
        for (int ht = 0; ht < 4; ++ht) o[ht][r] *= ar;
      }
    } else {
#pragma unroll
      for (int c = 0; c < 4; ++c)
#pragma unroll
        for (int r = 0; r < 4; ++r) {
          const float pv = __expf(vals[c][r] - m);
          vals[c][r] = pv;
          psum += pv;
        }
      psum += __shfl_xor(psum, 16);
      psum += __shfl_xor(psum, 32);
      l += psum;
    }

#pragma unroll
    for (int c = 0; c < 4; ++c) {
      uint2 pk;
      pk.x = (unsigned)f2bf(vals[c][0]) | ((unsigned)f2bf(vals[c][1]) << 16);
      pk.y = (unsigned)f2bf(vals[c][2]) | ((unsigned)f2bf(vals[c][3]) << 16);
      *(uint2*)(Pw + lq * 128 + ((32 * c + 8 * g) ^ swz)) = pk;
    }

    __builtin_amdgcn_s_setprio(1);
#pragma unroll
    for (int ht = 0; ht < 4; ++ht) {
      const int vb = (16 * ht + lq) << 7;
#pragma unroll
      for (int s = 0; s < 2; ++s) {
        const bf16x8 pf = *(const bf16x8*)(Pw + lq * 128 + ((64 * s + 16 * g) ^ swz));
        const bf16x8 vf = *(const bf16x8*)(Vs + ((vb + (s << 6) + (g << 4)) ^ swz));
        o[ht] = mfma16(pf, vf, o[ht]);
      }
    }
    __builtin_amdgcn_s_setprio(0);

    __syncthreads();
  }

  const int b = bh >> 4;
  const int h = bh & 15;
#pragma unroll
  for (int r = 0; r < 4; ++r) {
    const float linv = 1.0f / __shfl(l, 4 * g + r);
    const int srw = q0 + wid * 16 + 4 * g + r;
    const size_t base = ((size_t)(b * NB_S + srw)) * NB_D + h * NB_HD;
#pragma unroll
    for (int ht = 0; ht < 4; ++ht) {
      const float v = o[ht][r] * linv;
      const ushort hv = f2bf(v);
      OH[base + 16 * ht + lq] = hv;
      OL[base + 16 * ht + lq] = f2bf(v - bf2f(hv));
    }
  }
}

extern "C" void kernel_launch(void* const* d_in, const int* in_sizes, int n_in,
                              void* d_out, int out_size, void* d_ws, size_t ws_size,
                              hipStream_t stream) {
  const float* hs = (const float*)d_in[0];
  const float* wq = (const float*)d_in[1];
  const float* wk = (const float*)d_in[2];
  const float* wv = (const float*)d_in[3];
  const float* wo = (const float*)d_in[4];
  float* out = (float*)d_out;

  const size_t E = (size_t)NB_B * NB_S * NB_D;  // 4194304
  char* w = (char*)d_ws;
  ushort* WhiA = (ushort*)w;                    // 8 MB (4 weights hi)
  ushort* WloA = WhiA + ((size_t)4 << 20);      // 8 MB (4 weights lo)
  ushort* Ahi = WloA + ((size_t)4 << 20);       // 8 MB (hs hi; later attn hi)
  ushort* Alo = Ahi + E;                        // 8 MB (hs lo; later attn lo)
  ushort* Qd = Alo + E;                         // 8 MB (later wo partial-1 lo half)
  ushort* Kd = Qd + E;                          // 8 MB (later wo partial-1 hi half)
  ushort* Vt = Kd + E;                          // 8 MB
  float* tab = (float*)(Vt + E);                // 256 KB
  float* P1 = (float*)Qd;                       // 16 MB fp32, spans Qd+Kd

  // prep: split hs (2048) + split weights (2048) + rope table (128)
  k_prep<<<dim3(4224), 256, 0, stream>>>(hs, wq, wk, wv, wo, Ahi, Alo, WhiA, WloA, tab);

  // merged Q,K,V projection: one 768-block dispatch, 3 resident/CU
  k_gemm_mfma<0><<<dim3(768), 256, 0, stream>>>(
      Ahi, Alo, WhiA, WloA, (void*)Qd, (void*)Kd, (void*)Vt, tab);

  // attention writes split hi/lo into Ahi/Alo (dead after projections)
  k_attn<<<dim3(32, 32), 256, 0, stream>>>(Qd, Kd, Vt, Ahi, Alo);

  // output projection, split-K x2 (Qd/Kd dead -> P1 scratch), then reduce
  k_gemm_mfma<1><<<dim3(512), 256, 0, stream>>>(
      Ahi, Alo, WhiA + ((size_t)3 << 20), WloA + ((size_t)3 << 20),
      (void*)out, (void*)P1, (void*)nullptr, tab);
  k_red<<<dim3(2048), 256, 0, stream>>>(out, P1);
}